// Round 7
// baseline (235.253 us; speedup 1.0000x reference)
//
#include <hip/hip_runtime.h>
#include <hip/hip_bf16.h>

// WindowAttention v7: x-in-regs qkv (24KB LDS, 6 blk/CU) + per-window attn
// (grid 1024, 6-head loop, swapped QK^T/PV, b64 P stores, barrier-free).
// N=128 tokens, B_=1024 windows, C=192, H=6, hd=32.
// ws: bmF f32 [64*6][16384] ((bias+mask)*LOG2E, frag order (qf,kf)) |
//     wbf bf16[576][192] | pwbf bf16[192][192] |
//     q bf16 [b][h][n][32] (pre-scaled SCALE*LOG2E) | k same | v bf16 [b][h][32][128]
// attn bf16 out lives in d_out slot: d_out + b*98304 + 49152 (block-private).
// bm frag order: dst4[(qf*8+kf)*256 + tid][e] = bm[row=wave*32+qf*16+lr][k=kf*16+g*4+e]
// MFMA convention: mfma16(a,b): lane(g,lr) supplies a[row=lr][kd=8g+i], b[row=lr][kd=8g+i],
//   holds D[4g+rg][lr] (D-row = a-row space, D-col = b-row space).

typedef float f32x4 __attribute__((ext_vector_type(4)));
typedef short short8 __attribute__((ext_vector_type(8)));
typedef short short4e __attribute__((ext_vector_type(4)));

#define SCALE 0.17677669529663687f
#define LOG2E 1.4426950408889634f
#define QSC (SCALE * LOG2E)

static __device__ __forceinline__ short f2bf(float f) {
  __hip_bfloat16 h = __float2bfloat16(f);
  return __builtin_bit_cast(short, h);
}
static __device__ __forceinline__ f32x4 mfma16(short8 a, short8 b, f32x4 c) {
  return __builtin_amdgcn_mfma_f32_16x16x32_bf16(a, b, c, 0, 0, 0);
}

// ---------------- prep: convert qkv_w/proj_w to bf16 ----------------
__global__ __launch_bounds__(256) void prep_w(const float* __restrict__ qkvw,
                                              const float* __restrict__ projw,
                                              short* __restrict__ wbf,
                                              short* __restrict__ pwbf) {
  int t = blockIdx.x * 256 + threadIdx.x;  // float4 index 0..36863
  const int NQ = 27648;                    // 576*192/4
  float4 f; short* dst;
  if (t < NQ) { f = ((const float4*)qkvw)[t]; dst = wbf + t * 4; }
  else        { f = ((const float4*)projw)[t - NQ]; dst = pwbf + (t - NQ) * 4; }
  short4e o; o[0] = f2bf(f.x); o[1] = f2bf(f.y); o[2] = f2bf(f.z); o[3] = f2bf(f.w);
  *(short4e*)dst = o;
}

// ---------------- prep_bm: (bias+mask)*LOG2E, (qf,kf) fragment order, [w][h] tiles ----------------
__global__ __launch_bounds__(256) void prep_bm(const int* __restrict__ rel,
                                               const float* __restrict__ table,
                                               const float* __restrict__ mask,
                                               float* __restrict__ bmF) {
  int blk = blockIdx.x;            // 384 blocks: w*6 + h
  int w = blk / 6, h = blk - w * 6;
  int tid = threadIdx.x, lane = tid & 63, wave = tid >> 6;
  int lr = lane & 15, g = lane >> 4;
  const float* mk = mask + (size_t)w * 16384;
  float* dst = bmF + (size_t)blk * 16384;
#pragma unroll
  for (int L = 0; L < 16; ++L) {
    int qf = L >> 3, kf = L & 7;
    int row = wave * 32 + qf * 16 + lr;
    float4 v;
#pragma unroll
    for (int e = 0; e < 4; ++e) {
      int col = kf * 16 + g * 4 + e;
      float bias = table[rel[row * 128 + col] * 6 + h];
      ((float*)&v)[e] = (bias + mk[row * 128 + col]) * LOG2E;
    }
    ((float4*)dst)[L * 256 + tid] = v;
  }
}

// ---------------- qkv: x in registers, W through 24KB dbuf LDS ----------------
__global__ __launch_bounds__(256, 4) void qkv_kernel(const float* __restrict__ x,
                                                     const short* __restrict__ wbf,
                                                     short* __restrict__ qb,
                                                     short* __restrict__ kb,
                                                     short* __restrict__ vb) {
  __shared__ short wt[2][6144];  // [32][192] bf16 dbuf, swizzle byte ^= (row&7)<<4
  char* wtb = (char*)wt;
  const int b = blockIdx.x, tid = threadIdx.x;
  const int wave = tid >> 6, lane = tid & 63;
  const int lr = lane & 15, g = lane >> 4, g8 = g * 8, r4 = g * 4;
  const int rowbase = wave * 32;
  const int xorkey = (lr & 7) << 4;

  // W staging offsets: 768 granules of 16B per chunk, 3 per thread
  int wsoff[3], wdoff[3];
#pragma unroll
  for (int i = 0; i < 3; ++i) {
    int idx8 = i * 256 + tid;
    int r = idx8 / 24, c = idx8 - r * 24;
    wsoff[i] = idx8 * 8;  // shorts
    wdoff[i] = r * 384 + ((c * 16) ^ ((r & 7) << 4));
  }
  short8 wreg[3];
#pragma unroll
  for (int i = 0; i < 3; ++i) wreg[i] = *(const short8*)(wbf + wsoff[i]);  // chunk 0

  // x -> fragments (B-operand layout): rows rowbase+tf*16+lr, kdim g*8..
  short8 xa[2][6];
  {
    const float* xr = x + (size_t)b * 24576 + (size_t)(rowbase + lr) * 192;
#pragma unroll
    for (int tf = 0; tf < 2; ++tf)
#pragma unroll
      for (int ks = 0; ks < 6; ++ks) {
        const float* p = xr + tf * 16 * 192 + ks * 32 + g8;
        float4 f0 = *(const float4*)p;
        float4 f1 = *(const float4*)(p + 4);
        short8 v8;
        v8[0] = f2bf(f0.x); v8[1] = f2bf(f0.y); v8[2] = f2bf(f0.z); v8[3] = f2bf(f0.w);
        v8[4] = f2bf(f1.x); v8[5] = f2bf(f1.y); v8[6] = f2bf(f1.z); v8[7] = f2bf(f1.w);
        xa[tf][ks] = v8;
      }
  }
#pragma unroll
  for (int i = 0; i < 3; ++i) *(short8*)(wtb + wdoff[i]) = wreg[i];
  __syncthreads();

  for (int ch = 0; ch < 18; ++ch) {
    if (ch < 17) {
#pragma unroll
      for (int i = 0; i < 3; ++i)
        wreg[i] = *(const short8*)(wbf + (ch + 1) * 6144 + wsoff[i]);
    }
    const char* wb = wtb + (ch & 1) * 12288;
    f32x4 acc[2][2];
    acc[0][0] = acc[0][1] = acc[1][0] = acc[1][1] = f32x4{0.f, 0.f, 0.f, 0.f};
#pragma unroll
    for (int ks = 0; ks < 6; ++ks) {
      int cx = (ks * 64 + g * 16) ^ xorkey;
      short8 w0 = *(const short8*)(wb + lr * 384 + cx);
      short8 w1 = *(const short8*)(wb + (16 + lr) * 384 + cx);
      // swapped: D[w-col][token]
      acc[0][0] = mfma16(w0, xa[0][ks], acc[0][0]);
      acc[0][1] = mfma16(w0, xa[1][ks], acc[0][1]);
      acc[1][0] = mfma16(w1, xa[0][ks], acc[1][0]);
      acc[1][1] = mfma16(w1, xa[1][ks], acc[1][1]);
    }
    if (ch < 12) {
      short* dst = (ch < 6) ? qb : kb;
      int h = (ch < 6) ? ch : ch - 6;
      float sc = (ch < 6) ? QSC : 1.0f;
      size_t base = ((size_t)b * 6 + h) * 4096;
#pragma unroll
      for (int cf = 0; cf < 2; ++cf)
#pragma unroll
        for (int tf = 0; tf < 2; ++tf) {
          int tok = rowbase + tf * 16 + lr;
          short4e s4;
          s4[0] = f2bf(acc[cf][tf][0] * sc);
          s4[1] = f2bf(acc[cf][tf][1] * sc);
          s4[2] = f2bf(acc[cf][tf][2] * sc);
          s4[3] = f2bf(acc[cf][tf][3] * sc);
          *(short4e*)&dst[base + (size_t)tok * 32 + cf * 16 + r4] = s4;
        }
    } else {
      int h = ch - 12;
      size_t base = ((size_t)b * 6 + h) * 4096;
#pragma unroll
      for (int cf = 0; cf < 2; ++cf)
#pragma unroll
        for (int tf = 0; tf < 2; ++tf) {
          int tok = rowbase + tf * 16 + lr;
#pragma unroll
          for (int rg = 0; rg < 4; ++rg)
            vb[base + (size_t)(cf * 16 + r4 + rg) * 128 + tok] = f2bf(acc[cf][tf][rg]);
        }
    }
    if (ch < 17) {
#pragma unroll
      for (int i = 0; i < 3; ++i)
        *(short8*)(wtb + ((ch + 1) & 1) * 12288 + wdoff[i]) = wreg[i];
      __syncthreads();
    }
  }
}

// ---------------- attn: one block per window, 6 heads, barrier-free ----------------
__global__ __launch_bounds__(256, 5) void attn_kernel(const short* __restrict__ qb,
                                                      const short* __restrict__ kb,
                                                      const short* __restrict__ vb,
                                                      const float* __restrict__ bmF,
                                                      char* __restrict__ outc) {
  __shared__ short p_lds[16384];  // [128][128] bf16, swizzle byte ^= (row&15)<<4
  char* pbuf = (char*)p_lds;
  const int b = blockIdx.x;
  const int tid = threadIdx.x, wave = tid >> 6, lane = tid & 63;
  const int lr = lane & 15, g = lane >> 4, g8 = g * 8, r4 = g * 4;
  const int rowbase = wave * 32;
  const int swz = lr << 4;  // rows touched by this thread all have row&15 == lr
  short* outSlot = (short*)(outc + (size_t)b * 98304 + 49152);

#pragma unroll 1
  for (int h = 0; h < 6; ++h) {
    const size_t bh = (size_t)b * 6 + h;
    const short* qt = qb + bh * 4096;
    const short* kt = kb + bh * 4096;
    const short* vt = vb + bh * 4096;
    const float4* bm4 = (const float4*)(bmF + ((size_t)(b & 63) * 6 + h) * 16384);
    float inv[2];
#pragma unroll
    for (int qf = 0; qf < 2; ++qf) {
      // swapped QK^T: D[k-tok][q-tok]; lane holds q-row (rowbase+qf*16+lr),
      // k = kf*16 + 4g + rg
      short8 qa = *(const short8*)&qt[(rowbase + qf * 16 + lr) * 32 + g8];
      f32x4 s[8];
      __builtin_amdgcn_s_setprio(1);
#pragma unroll
      for (int kf = 0; kf < 8; ++kf) {
        short8 ka = *(const short8*)&kt[(kf * 16 + lr) * 32 + g8];
        f32x4 z = {0.f, 0.f, 0.f, 0.f};
        s[kf] = mfma16(ka, qa, z);
      }
      __builtin_amdgcn_s_setprio(0);
      float sum = 0.f;
      const int rowb = (rowbase + qf * 16 + lr) << 8;
#pragma unroll
      for (int kf = 0; kf < 8; ++kf) {
        float4 bm = bm4[(qf * 8 + kf) * 256 + tid];
        float p0 = exp2f(s[kf][0] + bm.x);
        float p1 = exp2f(s[kf][1] + bm.y);
        float p2 = exp2f(s[kf][2] + bm.z);
        float p3 = exp2f(s[kf][3] + bm.w);
        sum += (p0 + p1) + (p2 + p3);
        unsigned u0 = ((unsigned)(unsigned short)f2bf(p1) << 16) | (unsigned short)f2bf(p0);
        unsigned u1 = ((unsigned)(unsigned short)f2bf(p3) << 16) | (unsigned short)f2bf(p2);
        int2 wv; wv.x = (int)u0; wv.y = (int)u1;
        *(int2*)(pbuf + ((rowb + kf * 32 + g * 8) ^ swz)) = wv;
      }
      sum += __shfl_xor(sum, 16);
      sum += __shfl_xor(sum, 32);
      inv[qf] = 1.0f / sum;
    }
    // swapped PV: D[d][q-tok]; P wave-private, no barrier.
    f32x4 o_[2][2];
    o_[0][0] = o_[0][1] = o_[1][0] = o_[1][1] = f32x4{0.f, 0.f, 0.f, 0.f};
#pragma unroll
    for (int ks = 0; ks < 4; ++ks) {
      short8 va0 = *(const short8*)&vt[lr * 128 + ks * 32 + g8];
      short8 va1 = *(const short8*)&vt[(16 + lr) * 128 + ks * 32 + g8];
      short8 pb0 = *(const short8*)(pbuf + ((((rowbase + lr) << 8) + ks * 64 + g * 16) ^ swz));
      short8 pb1 = *(const short8*)(pbuf + ((((rowbase + 16 + lr) << 8) + ks * 64 + g * 16) ^ swz));
      __builtin_amdgcn_s_setprio(1);
      o_[0][0] = mfma16(va0, pb0, o_[0][0]);
      o_[0][1] = mfma16(va0, pb1, o_[0][1]);
      o_[1][0] = mfma16(va1, pb0, o_[1][0]);
      o_[1][1] = mfma16(va1, pb1, o_[1][1]);
      __builtin_amdgcn_s_setprio(0);
    }
#pragma unroll
    for (int df = 0; df < 2; ++df)
#pragma unroll
      for (int tf = 0; tf < 2; ++tf) {
        int tok = rowbase + tf * 16 + lr;
        short4e s4;
        s4[0] = f2bf(o_[df][tf][0] * inv[tf]);
        s4[1] = f2bf(o_[df][tf][1] * inv[tf]);
        s4[2] = f2bf(o_[df][tf][2] * inv[tf]);
        s4[3] = f2bf(o_[df][tf][3] * inv[tf]);
        *(short4e*)(outSlot + (size_t)tok * 192 + h * 32 + df * 16 + r4) = s4;
      }
  }
}

// ---------------- proj: ain[128][192] (bf16 in own d_out slot) @ proj_w^T + b ----------------
__global__ __launch_bounds__(256, 2) void proj_kernel(const short* __restrict__ pwbf,
                                                      const float* __restrict__ pb,
                                                      float* __restrict__ out) {
  __shared__ short at[24576];
  __shared__ short wt[2][6144];
  const int b = blockIdx.x, tid = threadIdx.x;
  const int wave = tid >> 6, lane = tid & 63;
  const int lr = lane & 15, g = lane >> 4;
  const int g16 = g * 16, r4 = g * 4;
  const int rowbase = wave * 32;
  const int xorkey = (lr & 7) << 4;
  char* atb = (char*)at;
  char* wtb = (char*)wt;

  int wsoff[3], wdoff[3];
#pragma unroll
  for (int i = 0; i < 3; ++i) {
    int idx8 = i * 256 + tid;
    int r = idx8 / 24, c = idx8 - r * 24;
    wsoff[i] = idx8 * 8;
    wdoff[i] = r * 384 + ((c * 16) ^ ((r & 7) << 4));
  }
  short8 wreg[3];
#pragma unroll
  for (int i = 0; i < 3; ++i) wreg[i] = *(const short8*)(pwbf + wsoff[i]);

  const short8* ar = (const short8*)((const char*)out + (size_t)b * 98304 + 49152);
#pragma unroll
  for (int i = 0; i < 12; ++i) {
    int idx8 = i * 256 + tid;
    int r = idx8 / 24, c = idx8 - r * 24;
    short8 v = ar[idx8];
    *(short8*)(atb + r * 384 + ((c * 16) ^ ((r & 7) << 4))) = v;
  }
#pragma unroll
  for (int i = 0; i < 3; ++i) *(short8*)(wtb + wdoff[i]) = wreg[i];
  __syncthreads();

  const int rA0 = (rowbase + lr) * 384, rA1 = rA0 + 16 * 384;
  const int wB0 = lr * 384, wB1 = wB0 + 16 * 384;

  for (int ch = 0; ch < 6; ++ch) {
    if (ch < 5) {
#pragma unroll
      for (int i = 0; i < 3; ++i)
        wreg[i] = *(const short8*)(pwbf + (ch + 1) * 6144 + wsoff[i]);
    }
    const char* wbuf = wtb + (ch & 1) * 12288;
    f32x4 acc[2][2];
    acc[0][0] = acc[0][1] = acc[1][0] = acc[1][1] = f32x4{0.f, 0.f, 0.f, 0.f};
#pragma unroll
    for (int ks = 0; ks < 6; ++ks) {
      int cx = (ks * 64 + g16) ^ xorkey;
      short8 xa0 = *(const short8*)(atb + rA0 + cx);
      short8 xa1 = *(const short8*)(atb + rA1 + cx);
      short8 wf0 = *(const short8*)(wbuf + wB0 + cx);
      short8 wf1 = *(const short8*)(wbuf + wB1 + cx);
      acc[0][0] = mfma16(xa0, wf0, acc[0][0]);
      acc[0][1] = mfma16(xa0, wf1, acc[0][1]);
      acc[1][0] = mfma16(xa1, wf0, acc[1][0]);
      acc[1][1] = mfma16(xa1, wf1, acc[1][1]);
    }
#pragma unroll
    for (int cf = 0; cf < 2; ++cf) {
      int j = ch * 32 + cf * 16 + lr;
      float bj = pb[j];
#pragma unroll
      for (int rf = 0; rf < 2; ++rf)
#pragma unroll
        for (int rg = 0; rg < 4; ++rg) {
          int tok = rowbase + rf * 16 + r4 + rg;
          out[((size_t)b * 128 + tok) * 192 + j] = acc[rf][cf][rg] + bj;
        }
    }
    if (ch < 5) {
#pragma unroll
      for (int i = 0; i < 3; ++i)
        *(short8*)(wtb + ((ch + 1) & 1) * 12288 + wdoff[i]) = wreg[i];
      __syncthreads();
    }
  }
}

extern "C" void kernel_launch(void* const* d_in, const int* in_sizes, int n_in,
                              void* d_out, int out_size, void* d_ws, size_t ws_size,
                              hipStream_t stream) {
  const float* x      = (const float*)d_in[0];
  const float* mask   = (const float*)d_in[1];
  const float* qkv_w  = (const float*)d_in[2];
  const float* proj_w = (const float*)d_in[3];
  const float* proj_b = (const float*)d_in[4];
  const float* table  = (const float*)d_in[5];
  const int*   rel    = (const int*)d_in[6];
  char* ws = (char*)d_ws;
  size_t o = 0;
  float* bmF  = (float*)(ws + o); o += 25165824;   // 384 * 16384 * 4
  short* wbf  = (short*)(ws + o); o += 221184;
  short* pwbf = (short*)(ws + o); o += 73728;
  short* qbp  = (short*)(ws + o); o += 50331648;
  short* kbp  = (short*)(ws + o); o += 50331648;
  short* vbp  = (short*)(ws + o); o += 50331648;
  float* out = (float*)d_out;

  prep_w<<<144, 256, 0, stream>>>(qkv_w, proj_w, wbf, pwbf);
  prep_bm<<<384, 256, 0, stream>>>(rel, table, mask, bmF);
  qkv_kernel<<<1024, 256, 0, stream>>>(x, wbf, qbp, kbp, vbp);
  attn_kernel<<<1024, 256, 0, stream>>>(qbp, kbp, vbp, bmF, (char*)d_out);
  proj_kernel<<<1024, 256, 0, stream>>>(pwbf, proj_b, (float*)d_out);
}